// Round 9
// baseline (194.767 us; speedup 1.0000x reference)
//
#include <hip/hip_runtime.h>
#include <hip/hip_bf16.h>
#include <cstdint>

typedef uint16_t u16;
typedef __attribute__((ext_vector_type(8))) short short8;
typedef __attribute__((ext_vector_type(4))) float f32x4;
typedef __attribute__((ext_vector_type(2))) float f32x2;
typedef __attribute__((ext_vector_type(4))) float fv4;

static constexpr int S = 4096;
static constexpr int D2 = 512;
static constexpr size_t RET_ELEMS = 16384ull * 512ull;      // retrieved floats
static constexpr float SCALE = 0.04419417382415922f;        // 512^-0.5

__device__ __forceinline__ u16 f2bf(float f) {
  uint32_t u = __float_as_uint(f);
  u += 0x7fffu + ((u >> 16) & 1u);
  return (u16)(u >> 16);
}

__device__ __forceinline__ float bflo(uint32_t u) { return __uint_as_float(u << 16); }
__device__ __forceinline__ float bfhi(uint32_t u) { return __uint_as_float(u & 0xffff0000u); }

// ---------------- zero fill: 268 MB attn region, pure streaming ----------
// 4096 blocks x 256 threads x 16 nt float4 stores = 16,777,216 float4s.
__global__ __launch_bounds__(256) void fill_zero_all(float* __restrict__ dst) {
  const fv4 z = {0.f, 0.f, 0.f, 0.f};
  const size_t tid = (size_t)blockIdx.x * 256 + threadIdx.x;
  #pragma unroll
  for (int k = 0; k < 16; ++k)
    __builtin_nontemporal_store(z, (fv4*)(dst + ((size_t)k * 1048576 + tid) * 4));
}

// ---------------- f32 -> bf16 cast ----------------
__global__ void cast_f32_bf16(const float* __restrict__ src, u16* __restrict__ dst, int n4) {
  int idx = blockIdx.x * blockDim.x + threadIdx.x;
  if (idx < n4) {
    float4 v = *(const float4*)(src + (size_t)idx * 4);
    ushort4 o;
    o.x = f2bf(v.x); o.y = f2bf(v.y); o.z = f2bf(v.z); o.w = f2bf(v.w);
    *(ushort4*)(dst + (size_t)idx * 4) = o;
  }
}

// ---------------- MbT[e][d] = bf16( SCALE * sum_k Wq[k][d] * Wk[k][e] ) ----
__global__ __launch_bounds__(256) void m_gemm(const float* __restrict__ Wq,
                                              const float* __restrict__ Wk,
                                              u16* __restrict__ MbT) {
  __shared__ float aq[8][32], ak[8][32];
  const int d0 = (blockIdx.x & 15) * 32;
  const int e0 = (blockIdx.x >> 4) * 32;
  const int tx = threadIdx.x & 15, ty = threadIdx.x >> 4;
  float acc[2][2] = {};
  for (int k0 = 0; k0 < 512; k0 += 8) {
    __syncthreads();
    const int r = threadIdx.x >> 5, c = threadIdx.x & 31;
    aq[r][c] = Wq[(size_t)(k0 + r) * 512 + d0 + c];
    ak[r][c] = Wk[(size_t)(k0 + r) * 512 + e0 + c];
    __syncthreads();
    #pragma unroll
    for (int kk = 0; kk < 8; ++kk) {
      const float q0 = aq[kk][2 * ty], q1 = aq[kk][2 * ty + 1];
      const float w0 = ak[kk][2 * tx], w1 = ak[kk][2 * tx + 1];
      acc[0][0] += q0 * w0; acc[0][1] += q0 * w1;
      acc[1][0] += q1 * w0; acc[1][1] += q1 * w1;
    }
  }
  #pragma unroll
  for (int a = 0; a < 2; ++a)
    #pragma unroll
    for (int c = 0; c < 2; ++c)
      MbT[(size_t)(e0 + 2 * tx + c) * 512 + d0 + 2 * ty + a] = f2bf(acc[a][c] * SCALE);
}

// ---------------- Q' = Xb * MbT^T  (bf16 in/out, f32 acc) ----------------
#define BM 128
#define BN 128
#define BK 32
#define LDSP 40

__global__ __launch_bounds__(256) void q_gemm(
    const u16* __restrict__ Xb, const u16* __restrict__ Bt, u16* __restrict__ Qp) {
  __shared__ u16 Xs[BM * LDSP];
  __shared__ u16 Ws[BN * LDSP];
  const int m0 = blockIdx.x * BM;
  const int n0 = blockIdx.y * BN;

  const int t = threadIdx.x;
  const int lane = t & 63, w = t >> 6;
  const int wm = w >> 1, wn = w & 1;
  const int r16 = lane & 15, kg = lane >> 4;
  const int srow = t >> 2, skcol = (t & 3) * 8;

  f32x4 acc[4][4] = {};

  for (int kt = 0; kt < D2; kt += BK) {
    __syncthreads();
    for (int p = 0; p < 2; ++p) {
      int row = srow + p * 64;
      uint4 va = *(const uint4*)(Xb + (size_t)(m0 + row) * D2 + kt + skcol);
      *(uint4*)(Xs + row * LDSP + skcol) = va;
      uint4 vb = *(const uint4*)(Bt + (size_t)(n0 + row) * D2 + kt + skcol);
      *(uint4*)(Ws + row * LDSP + skcol) = vb;
    }
    __syncthreads();
    short8 a[4], b[4];
    for (int f = 0; f < 4; ++f) {
      a[f] = *(const short8*)(Xs + (wm * 64 + f * 16 + r16) * LDSP + kg * 8);
      b[f] = *(const short8*)(Ws + (wn * 64 + f * 16 + r16) * LDSP + kg * 8);
    }
    for (int fm = 0; fm < 4; ++fm)
      for (int fn = 0; fn < 4; ++fn)
        acc[fm][fn] = __builtin_amdgcn_mfma_f32_16x16x32_bf16(a[fm], b[fn], acc[fm][fn], 0, 0, 0);
  }

  for (int fm = 0; fm < 4; ++fm) {
    int grow = m0 + wm * 64 + fm * 16 + kg * 4;
    for (int fn = 0; fn < 4; ++fn) {
      int gcol = n0 + wn * 64 + fn * 16 + r16;
      for (int r = 0; r < 4; ++r)
        Qp[(size_t)(grow + r) * D2 + gcol] = f2bf(acc[fm][fn][r]);
    }
  }
}

// ---------------- banded attention, band-only writes (zeros via fill) ----
// 1024 blocks x 256 threads (4 waves). Block = 16 queries. Each wave
// redundantly computes the 16x80 score tile (K == X via fold; B-frags from
// global, L2-resident under XCD swizzle); wave-private p_jm -> no barriers.
// Band rows split 4/wave; PV split by d-quarter per wave.
__global__ __launch_bounds__(256, 4) void attn_kernel(
    const u16* __restrict__ Qp, const u16* __restrict__ Xb, float* __restrict__ out) {
  __shared__ float p_jm[4][80][16];   // [wave][window col][query m]

  const int bid = blockIdx.x;
  const int swz = (bid & 7) * 128 + (bid >> 3);   // XCD-bijective
  const int w = threadIdx.x >> 6;
  const int lane = threadIdx.x & 63;
  const int qg = swz * 16;
  const int b = qg >> 12;
  const int i0 = qg & (S - 1);
  const int c15 = lane & 15, g = lane >> 4;

  const u16* xbat = Xb + (((size_t)b) << 12) * D2;
  const u16* qptr = Qp + (size_t)(qg + c15) * D2 + g * 8;
  const u16* kptr = xbat + (ptrdiff_t)(i0 - 64 + c15) * D2 + g * 8;  // <0 lands in Qp region: valid mem, masked

  // ---- QK^T: 16 k-steps x 5 key tiles ----
  f32x4 sc[5] = {};
  #pragma unroll 1
  for (int s = 0; s < 16; ++s) {
    const short8 qf = *(const short8*)(qptr + s * 32);
    #pragma unroll
    for (int t = 0; t < 5; ++t) {
      const short8 kf = *(const short8*)(kptr + t * (16 * D2) + s * 32);
      sc[t] = __builtin_amdgcn_mfma_f32_16x16x32_bf16(qf, kf, sc[t], 0, 0, 0);
    }
  }

  // ---- mask (scale folded into M). C layout: col=lane&15, row=4*(lane>>4)+r
  float sv[5][4];
  #pragma unroll
  for (int t = 0; t < 5; ++t)
    #pragma unroll
    for (int r = 0; r < 4; ++r) {
      const int m = 4 * g + r;
      const int rel = 16 * t + c15 - m;            // j - (i-64), valid in [0,64)
      const int j = i0 - 64 + 16 * t + c15;
      const bool ok = (rel >= 0) && (rel < 64) && (j >= 0);
      sv[t][r] = ok ? sc[t][r] : -INFINITY;
    }

  // ---- softmax per query row (16-lane group reduce) ----
  float p[5][4];
  #pragma unroll
  for (int r = 0; r < 4; ++r) {
    float mx = sv[0][r];
    #pragma unroll
    for (int t = 1; t < 5; ++t) mx = fmaxf(mx, sv[t][r]);
    #pragma unroll
    for (int off = 8; off; off >>= 1) mx = fmaxf(mx, __shfl_xor(mx, off));
    float e[5], sum = 0.f;
    #pragma unroll
    for (int t = 0; t < 5; ++t) {
      e[t] = (sv[t][r] == -INFINITY) ? 0.f : __expf(sv[t][r] - mx);
      sum += e[t];
    }
    #pragma unroll
    for (int off = 8; off; off >>= 1) sum += __shfl_xor(sum, off);
    const float rinv = (sum > 0.f) ? 1.f / sum : 0.f;
    #pragma unroll
    for (int t = 0; t < 5; ++t) p[t][r] = e[t] * rinv;
  }

  // ---- stash P (wave-private copy; no barrier needed) ----
  #pragma unroll
  for (int t = 0; t < 5; ++t)
    #pragma unroll
    for (int r = 0; r < 4; ++r)
      p_jm[w][16 * t + c15][4 * g + r] = p[t][r];

  // ---- band writes: wave w writes rows 4w + (lane>>4) ----
  {
    const int m2 = 4 * w + g;
    const int i = i0 + m2;
    if (i >= 1) {
      const int lo = (i >= 64) ? (i - 64) : 0;
      const int f0 = lo >> 2, f1 = (i - 1) >> 2;
      float* arow = out + RET_ELEMS + (size_t)(qg + m2) * S;
      #pragma unroll
      for (int pass = 0; pass < 2; ++pass) {
        const int f = f0 + c15 + 16 * pass;
        if (f <= f1) {
          fv4 v;
          #pragma unroll
          for (int c = 0; c < 4; ++c) {
            const int col = 4 * f + c;
            const bool in = (col >= lo) && (col < i);
            int rel = col - i0 + 64;
            rel = (rel < 0) ? 0 : (rel > 79 ? 79 : rel);
            v[c] = in ? p_jm[w][rel][m2] : 0.f;
          }
          __builtin_nontemporal_store(v, (fv4*)(arow + 4 * f));
        }
      }
    }
  }

  // ---- PV: wave w owns d-cols [128w, 128w+128); lane owns 2 bf16 cols ----
  f32x2 acc[16];
  #pragma unroll
  for (int m = 0; m < 16; ++m) acc[m] = (f32x2){0.f, 0.f};

  const int jstart = (i0 >= 64) ? 0 : (64 - i0);
  const u16* xcol = xbat + (ptrdiff_t)(i0 - 64) * D2 + w * 128 + lane * 2;
  #pragma unroll 2
  for (int j = jstart; j < 79; ++j) {
    const uint32_t xu = *(const uint32_t*)(xcol + (size_t)j * D2);
    const f32x2 xv = {bflo(xu), bfhi(xu)};
    alignas(16) float pall[16];
    *(float4*)&pall[0]  = *(const float4*)&p_jm[w][j][0];
    *(float4*)&pall[4]  = *(const float4*)&p_jm[w][j][4];
    *(float4*)&pall[8]  = *(const float4*)&p_jm[w][j][8];
    *(float4*)&pall[12] = *(const float4*)&p_jm[w][j][12];
    #pragma unroll
    for (int m = 0; m < 16; ++m)
      acc[m] += (f32x2){pall[m], pall[m]} * xv;
  }

  #pragma unroll
  for (int m = 0; m < 16; ++m) {
    float* rr = out + (size_t)(qg + m) * D2 + w * 128 + lane * 2;
    __builtin_nontemporal_store(acc[m], (f32x2*)rr);
  }
}

extern "C" void kernel_launch(void* const* d_in, const int* in_sizes, int n_in,
                              void* d_out, int out_size, void* d_ws, size_t ws_size,
                              hipStream_t stream) {
  const float* states = (const float*)d_in[0];
  const float* W_q    = (const float*)d_in[1];
  const float* W_k    = (const float*)d_in[2];
  float* out = (float*)d_out;

  char* ws = (char*)d_ws;
  u16* Qp  = (u16*)(ws);                 // 16 MB  (also absorbs masked negative-row reads)
  u16* Xb  = (u16*)(ws + 16777216);      // 16 MB
  u16* MbT = (u16*)(ws + 33554432);      // 0.5 MB

  // zero the whole attn region with our own streaming fill (~6.9 TB/s);
  // attn_kernel overwrites the band f4s afterwards (stream-ordered).
  fill_zero_all<<<4096, 256, 0, stream>>>(out + RET_ELEMS);

  cast_f32_bf16<<<8192, 256, 0, stream>>>(states, Xb, 2097152);
  m_gemm<<<256, 256, 0, stream>>>(W_q, W_k, MbT);
  q_gemm<<<dim3(128, 4), 256, 0, stream>>>(Xb, MbT, Qp);
  attn_kernel<<<1024, 256, 0, stream>>>(Qp, Xb, out);
}

// Round 10
// 141.376 us; speedup vs baseline: 1.3777x; 1.3777x over previous
//
#include <hip/hip_runtime.h>
#include <hip/hip_bf16.h>
#include <cstdint>

typedef uint16_t u16;
typedef __attribute__((ext_vector_type(8))) short short8;
typedef __attribute__((ext_vector_type(4))) float f32x4;
typedef __attribute__((ext_vector_type(2))) float f32x2;
typedef __attribute__((ext_vector_type(4))) float fv4;

static constexpr int S = 4096;
static constexpr int D2 = 512;
static constexpr size_t RET_ELEMS = 16384ull * 512ull;      // retrieved floats
static constexpr float SCALE = 0.04419417382415922f;        // 512^-0.5

__device__ __forceinline__ u16 f2bf(float f) {
  uint32_t u = __float_as_uint(f);
  u += 0x7fffu + ((u >> 16) & 1u);
  return (u16)(u >> 16);
}

__device__ __forceinline__ float bflo(uint32_t u) { return __uint_as_float(u << 16); }
__device__ __forceinline__ float bfhi(uint32_t u) { return __uint_as_float(u & 0xffff0000u); }

// ---------------- f32 -> bf16 cast ----------------
__global__ void cast_f32_bf16(const float* __restrict__ src, u16* __restrict__ dst, int n4) {
  int idx = blockIdx.x * blockDim.x + threadIdx.x;
  if (idx < n4) {
    float4 v = *(const float4*)(src + (size_t)idx * 4);
    ushort4 o;
    o.x = f2bf(v.x); o.y = f2bf(v.y); o.z = f2bf(v.z); o.w = f2bf(v.w);
    *(ushort4*)(dst + (size_t)idx * 4) = o;
  }
}

// ---------------- MbT[e][d] = bf16( SCALE * sum_k Wq[k][d] * Wk[k][e] ) ----
__global__ __launch_bounds__(256) void m_gemm(const float* __restrict__ Wq,
                                              const float* __restrict__ Wk,
                                              u16* __restrict__ MbT) {
  __shared__ float aq[8][32], ak[8][32];
  const int d0 = (blockIdx.x & 15) * 32;
  const int e0 = (blockIdx.x >> 4) * 32;
  const int tx = threadIdx.x & 15, ty = threadIdx.x >> 4;
  float acc[2][2] = {};
  for (int k0 = 0; k0 < 512; k0 += 8) {
    __syncthreads();
    const int r = threadIdx.x >> 5, c = threadIdx.x & 31;
    aq[r][c] = Wq[(size_t)(k0 + r) * 512 + d0 + c];
    ak[r][c] = Wk[(size_t)(k0 + r) * 512 + e0 + c];
    __syncthreads();
    #pragma unroll
    for (int kk = 0; kk < 8; ++kk) {
      const float q0 = aq[kk][2 * ty], q1 = aq[kk][2 * ty + 1];
      const float w0 = ak[kk][2 * tx], w1 = ak[kk][2 * tx + 1];
      acc[0][0] += q0 * w0; acc[0][1] += q0 * w1;
      acc[1][0] += q1 * w0; acc[1][1] += q1 * w1;
    }
  }
  #pragma unroll
  for (int a = 0; a < 2; ++a)
    #pragma unroll
    for (int c = 0; c < 2; ++c)
      MbT[(size_t)(e0 + 2 * tx + c) * 512 + d0 + 2 * ty + a] = f2bf(acc[a][c] * SCALE);
}

// ---------------- Q' = Xb * MbT^T  (bf16 in/out, f32 acc) ----------------
#define BM 128
#define BN 128
#define BK 32
#define LDSP 40

__global__ __launch_bounds__(256) void q_gemm(
    const u16* __restrict__ Xb, const u16* __restrict__ Bt, u16* __restrict__ Qp) {
  __shared__ u16 Xs[BM * LDSP];
  __shared__ u16 Ws[BN * LDSP];
  const int m0 = blockIdx.x * BM;
  const int n0 = blockIdx.y * BN;

  const int t = threadIdx.x;
  const int lane = t & 63, w = t >> 6;
  const int wm = w >> 1, wn = w & 1;
  const int r16 = lane & 15, kg = lane >> 4;
  const int srow = t >> 2, skcol = (t & 3) * 8;

  f32x4 acc[4][4] = {};

  for (int kt = 0; kt < D2; kt += BK) {
    __syncthreads();
    for (int p = 0; p < 2; ++p) {
      int row = srow + p * 64;
      uint4 va = *(const uint4*)(Xb + (size_t)(m0 + row) * D2 + kt + skcol);
      *(uint4*)(Xs + row * LDSP + skcol) = va;
      uint4 vb = *(const uint4*)(Bt + (size_t)(n0 + row) * D2 + kt + skcol);
      *(uint4*)(Ws + row * LDSP + skcol) = vb;
    }
    __syncthreads();
    short8 a[4], b[4];
    for (int f = 0; f < 4; ++f) {
      a[f] = *(const short8*)(Xs + (wm * 64 + f * 16 + r16) * LDSP + kg * 8);
      b[f] = *(const short8*)(Ws + (wn * 64 + f * 16 + r16) * LDSP + kg * 8);
    }
    for (int fm = 0; fm < 4; ++fm)
      for (int fn = 0; fn < 4; ++fn)
        acc[fm][fn] = __builtin_amdgcn_mfma_f32_16x16x32_bf16(a[fm], b[fn], acc[fm][fn], 0, 0, 0);
  }

  for (int fm = 0; fm < 4; ++fm) {
    int grow = m0 + wm * 64 + fm * 16 + kg * 4;
    for (int fn = 0; fn < 4; ++fn) {
      int gcol = n0 + wn * 64 + fn * 16 + r16;
      for (int r = 0; r < 4; ++r)
        Qp[(size_t)(grow + r) * D2 + gcol] = f2bf(acc[fm][fn][r]);
    }
  }
}

// ---------------- fused banded attention + interleaved zero fill ----------
// R5-proven structure + fold. 1024 blocks x 256 threads (4 waves). Block =
// 16 queries. Each wave redundantly computes the 16x80 score tile (K == X);
// nt zero-stores of the block's attn rows interleave with the QK s-loop
// (stores drain under MFMA); wave-private p_jm -> no barriers. Band rows
// split 4/wave; PV split by d-quarter per wave.
__global__ __launch_bounds__(256, 4) void attn_kernel(
    const u16* __restrict__ Qp, const u16* __restrict__ Xb, float* __restrict__ out) {
  __shared__ float p_jm[4][80][16];   // [wave][window col][query m]

  const int bid = blockIdx.x;
  const int swz = (bid & 7) * 128 + (bid >> 3);   // XCD-bijective
  const int w = threadIdx.x >> 6;
  const int lane = threadIdx.x & 63;
  const int qg = swz * 16;
  const int b = qg >> 12;
  const int i0 = qg & (S - 1);
  const int c15 = lane & 15, g = lane >> 4;

  const u16* xbat = Xb + (((size_t)b) << 12) * D2;
  const u16* qptr = Qp + (size_t)(qg + c15) * D2 + g * 8;
  const u16* kptr = xbat + (ptrdiff_t)(i0 - 64 + c15) * D2 + g * 8;  // <0 lands in Qp region: valid mem, masked
  float* azero = out + RET_ELEMS + (size_t)qg * S;

  // ---- QK^T: 16 k-steps x 5 key tiles, with interleaved nt zero-stores ----
  f32x4 sc[5] = {};
  const fv4 z4 = {0.f, 0.f, 0.f, 0.f};
  #pragma unroll 1
  for (int s = 0; s < 16; ++s) {
    const short8 qf = *(const short8*)(qptr + s * 32);
    // zero-stores: wave w covers rows 4w..4w+3, f4 col f = s*64 + lane
    #pragma unroll
    for (int r_ = 0; r_ < 4; ++r_) {
      const int rw = 4 * w + r_;
      const int i = i0 + rw;
      const int f = s * 64 + lane;
      const int flo = (i >= 64) ? ((i - 64) >> 2) : 0;
      const bool band = (i >= 1) && (f >= flo) && (f <= ((i - 1) >> 2));
      if (!band)
        __builtin_nontemporal_store(z4, (fv4*)(azero + (size_t)rw * S + 4 * f));
    }
    #pragma unroll
    for (int t = 0; t < 5; ++t) {
      const short8 kf = *(const short8*)(kptr + t * (16 * D2) + s * 32);
      sc[t] = __builtin_amdgcn_mfma_f32_16x16x32_bf16(qf, kf, sc[t], 0, 0, 0);
    }
  }

  // ---- mask (scale folded into M). C layout: col=lane&15, row=4*(lane>>4)+r
  float sv[5][4];
  #pragma unroll
  for (int t = 0; t < 5; ++t)
    #pragma unroll
    for (int r = 0; r < 4; ++r) {
      const int m = 4 * g + r;
      const int rel = 16 * t + c15 - m;            // j - (i-64), valid in [0,64)
      const int j = i0 - 64 + 16 * t + c15;
      const bool ok = (rel >= 0) && (rel < 64) && (j >= 0);
      sv[t][r] = ok ? sc[t][r] : -INFINITY;
    }

  // ---- softmax per query row (16-lane group reduce) ----
  float p[5][4];
  #pragma unroll
  for (int r = 0; r < 4; ++r) {
    float mx = sv[0][r];
    #pragma unroll
    for (int t = 1; t < 5; ++t) mx = fmaxf(mx, sv[t][r]);
    #pragma unroll
    for (int off = 8; off; off >>= 1) mx = fmaxf(mx, __shfl_xor(mx, off));
    float e[5], sum = 0.f;
    #pragma unroll
    for (int t = 0; t < 5; ++t) {
      e[t] = (sv[t][r] == -INFINITY) ? 0.f : __expf(sv[t][r] - mx);
      sum += e[t];
    }
    #pragma unroll
    for (int off = 8; off; off >>= 1) sum += __shfl_xor(sum, off);
    const float rinv = (sum > 0.f) ? 1.f / sum : 0.f;
    #pragma unroll
    for (int t = 0; t < 5; ++t) p[t][r] = e[t] * rinv;
  }

  // ---- stash P (wave-private copy; no barrier needed) ----
  #pragma unroll
  for (int t = 0; t < 5; ++t)
    #pragma unroll
    for (int r = 0; r < 4; ++r)
      p_jm[w][16 * t + c15][4 * g + r] = p[t][r];

  // ---- band writes: wave w writes rows 4w + (lane>>4) ----
  {
    const int m2 = 4 * w + g;
    const int i = i0 + m2;
    if (i >= 1) {
      const int lo = (i >= 64) ? (i - 64) : 0;
      const int f0 = lo >> 2, f1 = (i - 1) >> 2;
      float* arow = azero + (size_t)m2 * S;
      #pragma unroll
      for (int pass = 0; pass < 2; ++pass) {
        const int f = f0 + c15 + 16 * pass;
        if (f <= f1) {
          fv4 v;
          #pragma unroll
          for (int c = 0; c < 4; ++c) {
            const int col = 4 * f + c;
            const bool in = (col >= lo) && (col < i);
            int rel = col - i0 + 64;
            rel = (rel < 0) ? 0 : (rel > 79 ? 79 : rel);
            v[c] = in ? p_jm[w][rel][m2] : 0.f;
          }
          __builtin_nontemporal_store(v, (fv4*)(arow + 4 * f));
        }
      }
    }
  }

  // ---- PV: wave w owns d-cols [128w, 128w+128); lane owns 2 bf16 cols ----
  f32x2 acc[16];
  #pragma unroll
  for (int m = 0; m < 16; ++m) acc[m] = (f32x2){0.f, 0.f};

  const int jstart = (i0 >= 64) ? 0 : (64 - i0);
  const u16* xcol = xbat + (ptrdiff_t)(i0 - 64) * D2 + w * 128 + lane * 2;
  #pragma unroll 2
  for (int j = jstart; j < 79; ++j) {
    const uint32_t xu = *(const uint32_t*)(xcol + (size_t)j * D2);
    const f32x2 xv = {bflo(xu), bfhi(xu)};
    alignas(16) float pall[16];
    *(float4*)&pall[0]  = *(const float4*)&p_jm[w][j][0];
    *(float4*)&pall[4]  = *(const float4*)&p_jm[w][j][4];
    *(float4*)&pall[8]  = *(const float4*)&p_jm[w][j][8];
    *(float4*)&pall[12] = *(const float4*)&p_jm[w][j][12];
    #pragma unroll
    for (int m = 0; m < 16; ++m)
      acc[m] += (f32x2){pall[m], pall[m]} * xv;
  }

  #pragma unroll
  for (int m = 0; m < 16; ++m) {
    float* rr = out + (size_t)(qg + m) * D2 + w * 128 + lane * 2;
    __builtin_nontemporal_store(acc[m], (f32x2*)rr);
  }
}

extern "C" void kernel_launch(void* const* d_in, const int* in_sizes, int n_in,
                              void* d_out, int out_size, void* d_ws, size_t ws_size,
                              hipStream_t stream) {
  const float* states = (const float*)d_in[0];
  const float* W_q    = (const float*)d_in[1];
  const float* W_k    = (const float*)d_in[2];
  float* out = (float*)d_out;

  char* ws = (char*)d_ws;
  u16* Qp  = (u16*)(ws);                 // 16 MB  (also absorbs masked negative-row reads)
  u16* Xb  = (u16*)(ws + 16777216);      // 16 MB
  u16* MbT = (u16*)(ws + 33554432);      // 0.5 MB

  cast_f32_bf16<<<8192, 256, 0, stream>>>(states, Xb, 2097152);
  m_gemm<<<256, 256, 0, stream>>>(W_q, W_k, MbT);
  q_gemm<<<dim3(128, 4), 256, 0, stream>>>(Xb, MbT, Qp);
  attn_kernel<<<1024, 256, 0, stream>>>(Qp, Xb, out);
}

// Round 11
// 118.181 us; speedup vs baseline: 1.6480x; 1.1963x over previous
//
#include <hip/hip_runtime.h>
#include <hip/hip_bf16.h>
#include <cstdint>

typedef uint16_t u16;
typedef __attribute__((ext_vector_type(8))) short short8;
typedef __attribute__((ext_vector_type(4))) float f32x4;
typedef __attribute__((ext_vector_type(2))) float f32x2;
typedef __attribute__((ext_vector_type(4))) float fv4;
typedef __attribute__((ext_vector_type(4))) unsigned int u32x4;

static constexpr int S = 4096;
static constexpr int D2 = 512;
static constexpr size_t RET_ELEMS = 16384ull * 512ull;      // retrieved floats
static constexpr float SCALE = 0.04419417382415922f;        // 512^-0.5

__device__ __forceinline__ u16 f2bf(float f) {
  uint32_t u = __float_as_uint(f);
  u += 0x7fffu + ((u >> 16) & 1u);
  return (u16)(u >> 16);
}

__device__ __forceinline__ float bflo(uint32_t u) { return __uint_as_float(u << 16); }
__device__ __forceinline__ float bfhi(uint32_t u) { return __uint_as_float(u & 0xffff0000u); }

// ---------------- f32 -> bf16 cast ----------------
__global__ void cast_f32_bf16(const float* __restrict__ src, u16* __restrict__ dst, int n4) {
  int idx = blockIdx.x * blockDim.x + threadIdx.x;
  if (idx < n4) {
    float4 v = *(const float4*)(src + (size_t)idx * 4);
    ushort4 o;
    o.x = f2bf(v.x); o.y = f2bf(v.y); o.z = f2bf(v.z); o.w = f2bf(v.w);
    *(ushort4*)(dst + (size_t)idx * 4) = o;
  }
}

// ---------------- MbT[e][d] = bf16( SCALE * sum_k Wq[k][d] * Wk[k][e] ) ----
// v2: float4 staging, register double-buffer prefetch, 16 iterations.
__global__ __launch_bounds__(256) void m_gemm(const float* __restrict__ Wq,
                                              const float* __restrict__ Wk,
                                              u16* __restrict__ MbT) {
  __shared__ float aq[32][32], ak[32][32];
  const int d0 = (blockIdx.x & 15) * 32;
  const int e0 = (blockIdx.x >> 4) * 32;
  const int tx = threadIdx.x & 15, ty = threadIdx.x >> 4;
  const int lr = threadIdx.x >> 3, lc = (threadIdx.x & 7) * 4;   // stage row / col
  float acc00 = 0.f, acc01 = 0.f, acc10 = 0.f, acc11 = 0.f;

  float4 pq = *(const float4*)(Wq + (size_t)lr * 512 + d0 + lc);
  float4 pk = *(const float4*)(Wk + (size_t)lr * 512 + e0 + lc);

  for (int t = 0; t < 16; ++t) {
    __syncthreads();
    *(float4*)&aq[lr][lc] = pq;
    *(float4*)&ak[lr][lc] = pk;
    __syncthreads();
    if (t < 15) {
      const int k0 = (t + 1) * 32;
      pq = *(const float4*)(Wq + (size_t)(k0 + lr) * 512 + d0 + lc);
      pk = *(const float4*)(Wk + (size_t)(k0 + lr) * 512 + e0 + lc);
    }
    #pragma unroll
    for (int kk = 0; kk < 32; ++kk) {
      const float q0 = aq[kk][2 * ty], q1 = aq[kk][2 * ty + 1];
      const float w0 = ak[kk][2 * tx], w1 = ak[kk][2 * tx + 1];
      acc00 += q0 * w0; acc01 += q0 * w1;
      acc10 += q1 * w0; acc11 += q1 * w1;
    }
  }
  MbT[(size_t)(e0 + 2 * tx + 0) * 512 + d0 + 2 * ty + 0] = f2bf(acc00 * SCALE);
  MbT[(size_t)(e0 + 2 * tx + 1) * 512 + d0 + 2 * ty + 0] = f2bf(acc01 * SCALE);
  MbT[(size_t)(e0 + 2 * tx + 0) * 512 + d0 + 2 * ty + 1] = f2bf(acc10 * SCALE);
  MbT[(size_t)(e0 + 2 * tx + 1) * 512 + d0 + 2 * ty + 1] = f2bf(acc11 * SCALE);
}

// ---------------- Q' = Xb * MbT^T  (bf16 in/out, f32 acc) ----------------
#define BM 128
#define BN 128
#define BK 32
#define LDSP 40

__global__ __launch_bounds__(256) void q_gemm(
    const u16* __restrict__ Xb, const u16* __restrict__ Bt, u16* __restrict__ Qp) {
  __shared__ u16 Xs[BM * LDSP];
  __shared__ u16 Ws[BN * LDSP];
  const int m0 = blockIdx.x * BM;
  const int n0 = blockIdx.y * BN;

  const int t = threadIdx.x;
  const int lane = t & 63, w = t >> 6;
  const int wm = w >> 1, wn = w & 1;
  const int r16 = lane & 15, kg = lane >> 4;
  const int srow = t >> 2, skcol = (t & 3) * 8;

  f32x4 acc[4][4] = {};

  for (int kt = 0; kt < D2; kt += BK) {
    __syncthreads();
    for (int p = 0; p < 2; ++p) {
      int row = srow + p * 64;
      uint4 va = *(const uint4*)(Xb + (size_t)(m0 + row) * D2 + kt + skcol);
      *(uint4*)(Xs + row * LDSP + skcol) = va;
      uint4 vb = *(const uint4*)(Bt + (size_t)(n0 + row) * D2 + kt + skcol);
      *(uint4*)(Ws + row * LDSP + skcol) = vb;
    }
    __syncthreads();
    short8 a[4], b[4];
    for (int f = 0; f < 4; ++f) {
      a[f] = *(const short8*)(Xs + (wm * 64 + f * 16 + r16) * LDSP + kg * 8);
      b[f] = *(const short8*)(Ws + (wn * 64 + f * 16 + r16) * LDSP + kg * 8);
    }
    for (int fm = 0; fm < 4; ++fm)
      for (int fn = 0; fn < 4; ++fn)
        acc[fm][fn] = __builtin_amdgcn_mfma_f32_16x16x32_bf16(a[fm], b[fn], acc[fm][fn], 0, 0, 0);
  }

  for (int fm = 0; fm < 4; ++fm) {
    int grow = m0 + wm * 64 + fm * 16 + kg * 4;
    for (int fn = 0; fn < 4; ++fn) {
      int gcol = n0 + wn * 64 + fn * 16 + r16;
      for (int r = 0; r < 4; ++r)
        Qp[(size_t)(grow + r) * D2 + gcol] = f2bf(acc[fm][fn][r]);
    }
  }
}

// ---------------- fused banded attention + interleaved zero fill ----------
// 1024 blocks x 256 threads (4 waves). Block = 16 queries. Q' tile staged in
// LDS once (nontemporal global loads: Q' rows are single-consumer, keep them
// out of L2); X stays L2-cached (shared across neighbor blocks, ~2 MB/XCD).
// nt zero-stores interleave with the QK s-loop; wave-private p_jm.
__global__ __launch_bounds__(256, 4) void attn_kernel(
    const u16* __restrict__ Qp, const u16* __restrict__ Xb, float* __restrict__ out) {
  __shared__ u16 qlds[16 * 512];      // 16 KB, row stride 1024 B, XOR-swizzled
  __shared__ float p_jm[4][80][16];   // [wave][window col][query m]

  const int bid = blockIdx.x;
  const int swz = (bid & 7) * 128 + (bid >> 3);   // XCD-bijective
  const int w = threadIdx.x >> 6;
  const int lane = threadIdx.x & 63;
  const int qg = swz * 16;
  const int b = qg >> 12;
  const int i0 = qg & (S - 1);
  const int c15 = lane & 15, g = lane >> 4;

  const u16* xbat = Xb + (((size_t)b) << 12) * D2;
  const u16* kptr = xbat + (ptrdiff_t)(i0 - 64 + c15) * D2 + g * 8;  // <0 lands in Qp region: valid mem, masked
  float* azero = out + RET_ELEMS + (size_t)qg * S;

  // ---- stage Q' tile into swizzled LDS (each byte read once, nt) ----
  {
    const char* qsrc = (const char*)(Qp + (size_t)qg * D2);
    #pragma unroll
    for (int k2 = 0; k2 < 4; ++k2) {
      const int id = threadIdx.x + (k2 << 8);     // 16B chunk id, 0..1023
      const int row = id >> 6;                    // 0..15
      const int cb = (id & 63) << 4;              // byte col
      const u32x4 v = __builtin_nontemporal_load(
          (const u32x4*)(qsrc + (size_t)row * 1024 + cb));
      *(u32x4*)((char*)qlds + row * 1024 + (cb ^ ((row & 7) << 4))) = v;
    }
  }
  __syncthreads();

  // ---- QK^T: 16 k-steps x 5 key tiles, with interleaved nt zero-stores ----
  f32x4 sc[5] = {};
  const fv4 z4 = {0.f, 0.f, 0.f, 0.f};
  #pragma unroll 1
  for (int s = 0; s < 16; ++s) {
    const short8 qf = *(const short8*)((const char*)qlds + c15 * 1024 +
                                       ((g * 16 + s * 64) ^ ((c15 & 7) << 4)));
    // zero-stores: wave w covers rows 4w..4w+3, f4 col f = s*64 + lane
    #pragma unroll
    for (int r_ = 0; r_ < 4; ++r_) {
      const int rw = 4 * w + r_;
      const int i = i0 + rw;
      const int f = s * 64 + lane;
      const int flo = (i >= 64) ? ((i - 64) >> 2) : 0;
      const bool band = (i >= 1) && (f >= flo) && (f <= ((i - 1) >> 2));
      if (!band)
        __builtin_nontemporal_store(z4, (fv4*)(azero + (size_t)rw * S + 4 * f));
    }
    #pragma unroll
    for (int t = 0; t < 5; ++t) {
      const short8 kf = *(const short8*)(kptr + t * (16 * D2) + s * 32);
      sc[t] = __builtin_amdgcn_mfma_f32_16x16x32_bf16(qf, kf, sc[t], 0, 0, 0);
    }
  }

  // ---- mask (scale folded into M). C layout: col=lane&15, row=4*(lane>>4)+r
  float sv[5][4];
  #pragma unroll
  for (int t = 0; t < 5; ++t)
    #pragma unroll
    for (int r = 0; r < 4; ++r) {
      const int m = 4 * g + r;
      const int rel = 16 * t + c15 - m;            // j - (i-64), valid in [0,64)
      const int j = i0 - 64 + 16 * t + c15;
      const bool ok = (rel >= 0) && (rel < 64) && (j >= 0);
      sv[t][r] = ok ? sc[t][r] : -INFINITY;
    }

  // ---- softmax per query row (16-lane group reduce) ----
  float p[5][4];
  #pragma unroll
  for (int r = 0; r < 4; ++r) {
    float mx = sv[0][r];
    #pragma unroll
    for (int t = 1; t < 5; ++t) mx = fmaxf(mx, sv[t][r]);
    #pragma unroll
    for (int off = 8; off; off >>= 1) mx = fmaxf(mx, __shfl_xor(mx, off));
    float e[5], sum = 0.f;
    #pragma unroll
    for (int t = 0; t < 5; ++t) {
      e[t] = (sv[t][r] == -INFINITY) ? 0.f : __expf(sv[t][r] - mx);
      sum += e[t];
    }
    #pragma unroll
    for (int off = 8; off; off >>= 1) sum += __shfl_xor(sum, off);
    const float rinv = (sum > 0.f) ? 1.f / sum : 0.f;
    #pragma unroll
    for (int t = 0; t < 5; ++t) p[t][r] = e[t] * rinv;
  }

  // ---- stash P (wave-private copy; no barrier needed) ----
  #pragma unroll
  for (int t = 0; t < 5; ++t)
    #pragma unroll
    for (int r = 0; r < 4; ++r)
      p_jm[w][16 * t + c15][4 * g + r] = p[t][r];

  // ---- band writes: wave w writes rows 4w + (lane>>4) ----
  {
    const int m2 = 4 * w + g;
    const int i = i0 + m2;
    if (i >= 1) {
      const int lo = (i >= 64) ? (i - 64) : 0;
      const int f0 = lo >> 2, f1 = (i - 1) >> 2;
      float* arow = azero + (size_t)m2 * S;
      #pragma unroll
      for (int pass = 0; pass < 2; ++pass) {
        const int f = f0 + c15 + 16 * pass;
        if (f <= f1) {
          fv4 v;
          #pragma unroll
          for (int c = 0; c < 4; ++c) {
            const int col = 4 * f + c;
            const bool in = (col >= lo) && (col < i);
            int rel = col - i0 + 64;
            rel = (rel < 0) ? 0 : (rel > 79 ? 79 : rel);
            v[c] = in ? p_jm[w][rel][m2] : 0.f;
          }
          __builtin_nontemporal_store(v, (fv4*)(arow + 4 * f));
        }
      }
    }
  }

  // ---- PV: wave w owns d-cols [128w, 128w+128); lane owns 2 bf16 cols ----
  f32x2 acc[16];
  #pragma unroll
  for (int m = 0; m < 16; ++m) acc[m] = (f32x2){0.f, 0.f};

  const int jstart = (i0 >= 64) ? 0 : (64 - i0);
  const u16* xcol = xbat + (ptrdiff_t)(i0 - 64) * D2 + w * 128 + lane * 2;
  #pragma unroll 2
  for (int j = jstart; j < 79; ++j) {
    const uint32_t xu = *(const uint32_t*)(xcol + (size_t)j * D2);
    const f32x2 xv = {bflo(xu), bfhi(xu)};
    alignas(16) float pall[16];
    *(float4*)&pall[0]  = *(const float4*)&p_jm[w][j][0];
    *(float4*)&pall[4]  = *(const float4*)&p_jm[w][j][4];
    *(float4*)&pall[8]  = *(const float4*)&p_jm[w][j][8];
    *(float4*)&pall[12] = *(const float4*)&p_jm[w][j][12];
    #pragma unroll
    for (int m = 0; m < 16; ++m)
      acc[m] += (f32x2){pall[m], pall[m]} * xv;
  }

  #pragma unroll
  for (int m = 0; m < 16; ++m) {
    float* rr = out + (size_t)(qg + m) * D2 + w * 128 + lane * 2;
    __builtin_nontemporal_store(acc[m], (f32x2*)rr);
  }
}

extern "C" void kernel_launch(void* const* d_in, const int* in_sizes, int n_in,
                              void* d_out, int out_size, void* d_ws, size_t ws_size,
                              hipStream_t stream) {
  const float* states = (const float*)d_in[0];
  const float* W_q    = (const float*)d_in[1];
  const float* W_k    = (const float*)d_in[2];
  float* out = (float*)d_out;

  char* ws = (char*)d_ws;
  u16* Qp  = (u16*)(ws);                 // 16 MB  (also absorbs masked negative-row reads)
  u16* Xb  = (u16*)(ws + 16777216);      // 16 MB
  u16* MbT = (u16*)(ws + 33554432);      // 0.5 MB

  cast_f32_bf16<<<8192, 256, 0, stream>>>(states, Xb, 2097152);
  m_gemm<<<256, 256, 0, stream>>>(W_q, W_k, MbT);
  q_gemm<<<dim3(128, 4), 256, 0, stream>>>(Xb, MbT, Qp);
  attn_kernel<<<1024, 256, 0, stream>>>(Qp, Xb, out);
}